// Round 13
// baseline (1295.458 us; speedup 1.0000x reference)
//
#include <hip/hip_runtime.h>
#include <math.h>

#define WIDTH 256
#define PTS 16
#define NROW 80            // 5 chains * 16 points
#define CPLANE 20480       // halves per component plane per tile: 5v * 8kc * 64lane * 8

typedef _Float16 f16x8 __attribute__((ext_vector_type(8)));
typedef _Float16 f16x4 __attribute__((ext_vector_type(4)));
typedef __fp16   h16x2 __attribute__((ext_vector_type(2)));   // cvt_pkrtz return type
typedef float    f32x4 __attribute__((ext_vector_type(4)));

// fp32 -> fp16 hi + fp16 lo (2-split, covers ~22-24 mantissa bits)
__device__ __forceinline__ void split2(float f, _Float16& h, _Float16& l) {
    h = (_Float16)f;
    l = (_Float16)(f - (float)h);
}
// z=tanh(u), s=1-z^2 = 4t/(1+t)^2 with t=exp(-2|u|): no cancellation in saturation
__device__ __forceinline__ void tanh_s(float u, float& z, float& s) {
    const float t = __expf(-2.0f * fabsf(u));
    const float r = 1.0f / (1.0f + t);
    const float zm = (1.0f - t) * r;
    z = copysignf(zm, u);
    s = 4.0f * t * r * r;
}

// Pre-split w1..w5 into fp16 hi/lo, transposed + packed in MFMA A-frag order:
// wt2[(l*2+c)*65536 + ((jt*8+kc)*64 + lane)*8 + i] = comp_c(W[k][j]),
// j = jt*16 + (lane&15), k = kc*32 + (lane>>4)*8 + i.
__global__ void prep_w_kernel(const float* __restrict__ w1, const float* __restrict__ w2,
                              const float* __restrict__ w3, const float* __restrict__ w4,
                              const float* __restrict__ w5, _Float16* __restrict__ wt2)
{
    const int idx = blockIdx.x * blockDim.x + threadIdx.x;
    if (idx >= 5 * 16 * 8 * 64) return;
    const int lane = idx & 63;
    const int kc   = (idx >> 6) & 7;
    const int jt   = (idx >> 9) & 15;
    const int l    = idx >> 13;
    const float* Wsrc[5] = { w1, w2, w3, w4, w5 };
    const float* W = Wsrc[l];
    const int j  = jt * 16 + (lane & 15);
    const int k0 = kc * 32 + (lane >> 4) * 8;
    f16x8 vh, vl;
    #pragma unroll
    for (int i = 0; i < 8; ++i) {
        _Float16 h, lo;
        split2(W[(k0 + i) * WIDTH + j], h, lo);
        vh[i] = h; vl[i] = lo;
    }
    const int fo = ((jt * 8 + kc) * 64 + lane) * 8;
    *(f16x8*)(wt2 + (l * 2 + 0) * 65536 + fo) = vh;
    *(f16x8*)(wt2 + (l * 2 + 1) * 65536 + fo) = vl;
}

// Two tiles per block, one layer out of phase: each stage interleaves tile X's
// MFMA k-loop with tile Y's VALU epilogue in ONE instruction stream -> the
// scheduler overlaps matrix and vector pipes within the wave (R12 showed
// cross-wave anti-phasing never happens; barriers lock phases).
// LDS = 2 tiles * 81920 = 163840 B (full CU) -> 1 block/CU, 8 waves.
__global__ __launch_bounds__(512, 2)
void pde_mfma_kernel(const float* __restrict__ xyt,
                     const float* __restrict__ w0, const float* __restrict__ b0,
                     const float* __restrict__ b1, const float* __restrict__ b2,
                     const float* __restrict__ b3, const float* __restrict__ b4,
                     const float* __restrict__ b5,
                     const float* __restrict__ w6, const float* __restrict__ b6,
                     const _Float16* __restrict__ wt2,
                     float* __restrict__ out)
{
    __shared__ _Float16 Zs[4 * CPLANE];   // [tile][comp][CPLANE], 163840 B exactly
    float* redf = (float*)Zs;             // aliased reduction scratch (after last Z read)

    const int tid  = threadIdx.x;
    const int lane = tid & 63;
    const int wv   = tid >> 6;       // wave 0..7 -> M-tiles {2w, 2w+1}
    const int q    = lane >> 4;
    const int n15  = lane & 15;
    const long tile0 = (long)blockIdx.x * 2;
    const float* Bsl[5] = { b1, b2, b3, b4, b5 };

    _Float16* ZA = Zs;
    _Float16* ZB = Zs + 2 * CPLANE;

    // ---------------- layer 0: (3 -> 256), Taylor-mode, fp32 VALU, both tiles ----
    #pragma unroll
    for (int tl = 0; tl < 2; ++tl) {
        _Float16* Zt = tl ? ZB : ZA;
        const long gp0 = (tile0 + tl) * PTS;
        const int p  = tid & 15;
        const int jg = tid >> 4;            // 0..31, 8 features each
        const float x = xyt[(gp0 + p) * 3 + 0];
        const float y = xyt[(gp0 + p) * 3 + 1];
        const float t = xyt[(gp0 + p) * 3 + 2];
        f16x8 vh[5], vl[5];
        #pragma unroll
        for (int c = 0; c < 8; ++c) {
            const int j = jg * 8 + c;
            const float wx = w0[0 * WIDTH + j];
            const float wy = w0[1 * WIDTH + j];
            const float wt = w0[2 * WIDTH + j];
            float zv, s;
            tanh_s(fmaf(x, wx, fmaf(y, wy, fmaf(t, wt, b0[j]))), zv, s);
            const float vals[5] = { zv, s * wx, s * wy, s * wt,
                                    -2.0f * zv * s * (wx * wx + wy * wy) };
            #pragma unroll
            for (int v = 0; v < 5; ++v) {
                _Float16 h, lo;
                split2(vals[v], h, lo);
                vh[v][c] = h; vl[v][c] = lo;
            }
        }
        #pragma unroll
        for (int v = 0; v < 5; ++v) {
            const int off = ((v * 8 + (jg >> 2)) * 64 + (jg & 3) * 16 + p) * 8;
            *(f16x8*)(Zt + off)          = vh[v];
            *(f16x8*)(Zt + CPLANE + off) = vl[v];
        }
    }
    __syncthreads();

    // ---------------- hidden layers: interleaved two-tile pipeline ----------
    f32x4 accA[5][2], accB[5][2];

    auto zacc = [&](f32x4 (&acc)[5][2]) {
        #pragma unroll
        for (int v = 0; v < 5; ++v)
            #pragma unroll
            for (int Mt = 0; Mt < 2; ++Mt)
                acc[v][Mt] = (f32x4){0.f, 0.f, 0.f, 0.f};
    };

    auto kstage = [&](const _Float16* __restrict__ Zt, const _Float16* __restrict__ Wl,
                      f32x4 (&acc)[5][2]) {
        #pragma unroll 2
        for (int kc = 0; kc < 8; ++kc) {
            f16x8 Ah[2], Al[2];
            #pragma unroll
            for (int Mt = 0; Mt < 2; ++Mt) {
                const int fo = (((wv * 2 + Mt) * 8 + kc) * 64 + lane) * 8;
                Ah[Mt] = *(const f16x8*)(Wl + fo);
                Al[Mt] = *(const f16x8*)(Wl + 65536 + fo);
            }
            #pragma unroll
            for (int v = 0; v < 5; ++v) {
                const int zo = ((v * 8 + kc) * 64 + lane) * 8;
                const f16x8 Bh = *(const f16x8*)(Zt + zo);
                const f16x8 Bl = *(const f16x8*)(Zt + CPLANE + zo);
                #pragma unroll
                for (int Mt = 0; Mt < 2; ++Mt) {
                    f32x4 a = acc[v][Mt];
                    a = __builtin_amdgcn_mfma_f32_16x16x32_f16(Ah[Mt], Bl, a, 0, 0, 0);
                    a = __builtin_amdgcn_mfma_f32_16x16x32_f16(Al[Mt], Bh, a, 0, 0, 0);
                    a = __builtin_amdgcn_mfma_f32_16x16x32_f16(Ah[Mt], Bh, a, 0, 0, 0);
                    acc[v][Mt] = a;
                }
            }
        }
    };

    auto estage = [&](_Float16* __restrict__ Zt, const float* __restrict__ Bb,
                      f32x4 (&acc)[5][2]) {
        #pragma unroll
        for (int Mt = 0; Mt < 2; ++Mt) {
            const int jt = wv * 2 + Mt;
            float nv[5][4];
            #pragma unroll
            for (int reg = 0; reg < 4; ++reg) {
                const int j = jt * 16 + q * 4 + reg;
                float zv, s;
                tanh_s(acc[0][Mt][reg] + Bb[j], zv, s);
                const float u1 = acc[1][Mt][reg];
                const float u2 = acc[2][Mt][reg];
                nv[0][reg] = zv;
                nv[1][reg] = s * u1;
                nv[2][reg] = s * u2;
                nv[3][reg] = s * acc[3][Mt][reg];
                nv[4][reg] = fmaf(-2.0f * zv * s, fmaf(u1, u1, u2 * u2),
                                  s * acc[4][Mt][reg]);
            }
            const int j0 = jt * 16 + q * 4;
            const int off0 = ((j0 >> 5) * 64 + ((j0 >> 3) & 3) * 16 + n15) * 8 + (j0 & 7);
            #pragma unroll
            for (int v = 0; v < 5; ++v) {
                const h16x2 h01 = __builtin_amdgcn_cvt_pkrtz(nv[v][0], nv[v][1]);
                const h16x2 h23 = __builtin_amdgcn_cvt_pkrtz(nv[v][2], nv[v][3]);
                const h16x2 l01 = __builtin_amdgcn_cvt_pkrtz(nv[v][0] - (float)h01[0],
                                                             nv[v][1] - (float)h01[1]);
                const h16x2 l23 = __builtin_amdgcn_cvt_pkrtz(nv[v][2] - (float)h23[0],
                                                             nv[v][3] - (float)h23[1]);
                *(f16x4*)(Zt + v * 4096 + off0) =
                    (f16x4){ (_Float16)h01[0], (_Float16)h01[1],
                             (_Float16)h23[0], (_Float16)h23[1] };
                *(f16x4*)(Zt + CPLANE + v * 4096 + off0) =
                    (f16x4){ (_Float16)l01[0], (_Float16)l01[1],
                             (_Float16)l23[0], (_Float16)l23[1] };
            }
        }
    };

    // pipeline: K_A1 | K_B(l)+E_A(l) | K_A(l+1)+E_B(l) | ... | E_B5
    zacc(accA);
    kstage(ZA, wt2, accA);
    __syncthreads();
    for (int l = 1; l <= 5; ++l) {
        zacc(accB);
        kstage(ZB, wt2 + (l - 1) * 2 * 65536, accB);   // K_B(l)
        estage(ZA, Bsl[l - 1], accA);                  // E_A(l)
        __syncthreads();
        if (l < 5) {
            zacc(accA);
            kstage(ZA, wt2 + l * 2 * 65536, accA);     // K_A(l+1)
        }
        estage(ZB, Bsl[l - 1], accB);                  // E_B(l)
        __syncthreads();
    }

    // ---------------- final layer: (256 -> 1) dot products, both tiles -------
    float pT[2] = { 0.f, 0.f };
    const int n  = tid >> 2;          // row 0..79 (valid if tid < 320)
    const int ch = tid & 3;           // feature chunk
    if (tid < 4 * NROW) {
        const int v = n >> 4, p = n & 15;
        #pragma unroll
        for (int tl = 0; tl < 2; ++tl) {
            const _Float16* Zt = tl ? ZB : ZA;
            float partial = 0.f;
            for (int kk = ch * 64; kk < ch * 64 + 64; kk += 8) {
                const int off = ((v * 8 + (kk >> 5)) * 64 + ((kk >> 3) & 3) * 16 + p) * 8;
                const f16x8 zh = *(const f16x8*)(Zt + off);
                const f16x8 zl = *(const f16x8*)(Zt + CPLANE + off);
                #pragma unroll
                for (int i = 0; i < 8; ++i)
                    partial = fmaf((float)zh[i] + (float)zl[i], w6[kk + i], partial);
            }
            pT[tl] = partial;
        }
    }
    __syncthreads();                 // all reads of Zs done before aliasing redf
    if (tid < 4 * NROW) {
        redf[0 * 400 + ch * NROW + n] = pT[0];
        redf[1 * 400 + ch * NROW + n] = pT[1];
    }
    __syncthreads();
    if (tid < 2 * NROW) {
        const int tl = tid >> 7 ? 1 : 0;       // unused split; compute directly:
    }
    if (tid < NROW) {
        redf[0 * 400 + 320 + tid] = redf[tid] + redf[NROW + tid] +
                                    redf[2 * NROW + tid] + redf[3 * NROW + tid];
        redf[1 * 400 + 320 + tid] = redf[400 + tid] + redf[400 + NROW + tid] +
                                    redf[400 + 2 * NROW + tid] + redf[400 + 3 * NROW + tid];
    }
    __syncthreads();

    // ---------------- residual: 32 points ----------------
    if (tid < 2 * PTS) {
        const int tl = tid >> 4;
        const int p  = tid & 15;
        const long gp0 = (tile0 + tl) * PTS;
        const float* tot = redf + tl * 400 + 320;
        const float h   = tot[0 * 16 + p] + b6[0];
        const float hx  = tot[1 * 16 + p];
        const float hy  = tot[2 * 16 + p];
        const float ht  = tot[3 * 16 + p];
        const float lap = tot[4 * 16 + p];
        const float x = xyt[(gp0 + p) * 3 + 0];
        const float y = xyt[(gp0 + p) * 3 + 1];
        const float t = xyt[(gp0 + p) * 3 + 2];
        const float pi = 3.14159265358979323846f;
        const float f = sinf(pi * x) * sinf(pi * y) * expf(-t);
        out[gp0 + p] = ht - 0.5f * (fmaf(h, lap, fmaf(hx, hx, hy * hy))) - f;
    }
}

extern "C" void kernel_launch(void* const* d_in, const int* in_sizes, int n_in,
                              void* d_out, int out_size, void* d_ws, size_t ws_size,
                              hipStream_t stream) {
    const float* xyt = (const float*)d_in[0];
    const float* w0  = (const float*)d_in[1];
    const float* b0  = (const float*)d_in[2];
    const float* w1  = (const float*)d_in[3];
    const float* b1  = (const float*)d_in[4];
    const float* w2  = (const float*)d_in[5];
    const float* b2  = (const float*)d_in[6];
    const float* w3  = (const float*)d_in[7];
    const float* b3  = (const float*)d_in[8];
    const float* w4  = (const float*)d_in[9];
    const float* b4  = (const float*)d_in[10];
    const float* w5  = (const float*)d_in[11];
    const float* b5  = (const float*)d_in[12];
    const float* w6  = (const float*)d_in[13];
    const float* b6  = (const float*)d_in[14];
    float* out = (float*)d_out;
    _Float16* wt2 = (_Float16*)d_ws;    // needs 5*2*65536*2 = 1,310,720 B

    prep_w_kernel<<<160, 256, 0, stream>>>(w1, w2, w3, w4, w5, wt2);

    const int npts = in_sizes[0] / 3;   // 131072
    dim3 grid(npts / (PTS * 2));        // 4096 blocks x 2 tiles
    dim3 block(512);
    pde_mfma_kernel<<<grid, block, 0, stream>>>(xyt, w0, b0, b1, b2, b3, b4, b5,
                                                w6, b6, wt2, out);
}

// Round 14
// 1182.940 us; speedup vs baseline: 1.0951x; 1.0951x over previous
//
#include <hip/hip_runtime.h>
#include <math.h>

#define WIDTH 256
#define PTS 16
#define NROW 80            // 5 chains * 16 points
#define CPLANE 20480       // halves per component plane per tile: 5v * 8kc * 64lane * 8

typedef _Float16 f16x8 __attribute__((ext_vector_type(8)));
typedef _Float16 f16x4 __attribute__((ext_vector_type(4)));
typedef __fp16   h16x2 __attribute__((ext_vector_type(2)));   // cvt_pkrtz return type
typedef float    f32x4 __attribute__((ext_vector_type(4)));

// fp32 -> fp16 hi + fp16 lo (2-split, covers ~22-24 mantissa bits)
__device__ __forceinline__ void split2(float f, _Float16& h, _Float16& l) {
    h = (_Float16)f;
    l = (_Float16)(f - (float)h);
}
// z=tanh(u), s=1-z^2 = 4t/(1+t)^2 with t=exp(-2|u|): no cancellation in saturation
__device__ __forceinline__ void tanh_s(float u, float& z, float& s) {
    const float t = __expf(-2.0f * fabsf(u));
    const float r = 1.0f / (1.0f + t);
    const float zm = (1.0f - t) * r;
    z = copysignf(zm, u);
    s = 4.0f * t * r * r;
}

// Pre-split w1..w5 into fp16 hi/lo, transposed + packed in MFMA A-frag order:
// wt2[(l*2+c)*65536 + ((jt*8+kc)*64 + lane)*8 + i] = comp_c(W[k][j]),
// j = jt*16 + (lane&15), k = kc*32 + (lane>>4)*8 + i.
__global__ void prep_w_kernel(const float* __restrict__ w1, const float* __restrict__ w2,
                              const float* __restrict__ w3, const float* __restrict__ w4,
                              const float* __restrict__ w5, _Float16* __restrict__ wt2)
{
    const int idx = blockIdx.x * blockDim.x + threadIdx.x;
    if (idx >= 5 * 16 * 8 * 64) return;
    const int lane = idx & 63;
    const int kc   = (idx >> 6) & 7;
    const int jt   = (idx >> 9) & 15;
    const int l    = idx >> 13;
    const float* Wsrc[5] = { w1, w2, w3, w4, w5 };
    const float* W = Wsrc[l];
    const int j  = jt * 16 + (lane & 15);
    const int k0 = kc * 32 + (lane >> 4) * 8;
    f16x8 vh, vl;
    #pragma unroll
    for (int i = 0; i < 8; ++i) {
        _Float16 h, lo;
        split2(W[(k0 + i) * WIDTH + j], h, lo);
        vh[i] = h; vl[i] = lo;
    }
    const int fo = ((jt * 8 + kc) * 64 + lane) * 8;
    *(f16x8*)(wt2 + (l * 2 + 0) * 65536 + fo) = vh;
    *(f16x8*)(wt2 + (l * 2 + 1) * 65536 + fo) = vl;
}

// Producer/consumer gang anti-phasing (m114: MFMA-wave + VALU-wave co-schedule):
// block = 8 waves = 2 gangs of 4. Gang A owns tile A, gang B owns tile B,
// offset by half a layer: every phase has one gang in the MFMA k-loop and the
// other in the VALU epilogue. Wave i -> SIMD i%4 puts 1 A-wave + 1 B-wave per
// SIMD. Each gang keeps one acc set (no R13 dual-acc register blowup).
// LDS = 2 tiles * 81920 B = 163840 B (full CU) -> 1 block/CU.
__global__ __launch_bounds__(512, 2)
void pde_mfma_kernel(const float* __restrict__ xyt,
                     const float* __restrict__ w0, const float* __restrict__ b0,
                     const float* __restrict__ b1, const float* __restrict__ b2,
                     const float* __restrict__ b3, const float* __restrict__ b4,
                     const float* __restrict__ b5,
                     const float* __restrict__ w6, const float* __restrict__ b6,
                     const _Float16* __restrict__ wt2,
                     float* __restrict__ out)
{
    __shared__ _Float16 Zs[4 * CPLANE];   // [tileA: hi|lo][tileB: hi|lo]

    const int tid  = threadIdx.x;
    const int wv8  = tid >> 6;            // block wave 0..7
    const bool isA = wv8 < 4;             // waves 0-3 gang A, 4-7 gang B
    const int gtid = tid & 255;           // gang-local thread id
    const int gwv  = gtid >> 6;           // gang-local wave 0..3 -> M-tiles 4g..4g+3
    const int lane = tid & 63;
    const int q    = lane >> 4;
    const int n15  = lane & 15;

    _Float16* Zm  = Zs + (isA ? 0 : 2 * CPLANE);   // my gang's tile state
    float* redf   = (float*)Zm;                    // aliased scratch (after last Z read)
    const long gp0 = ((long)blockIdx.x * 2 + (isA ? 0 : 1)) * PTS;
    const float* Bsl[5] = { b1, b2, b3, b4, b5 };

    // ---------------- layer 0: both gangs stage their own tile (VALU) -------
    {
        const int p = gtid & 15;
        const float x = xyt[(gp0 + p) * 3 + 0];
        const float y = xyt[(gp0 + p) * 3 + 1];
        const float t = xyt[(gp0 + p) * 3 + 2];
        #pragma unroll
        for (int half = 0; half < 2; ++half) {
            const int jg = (gtid >> 4) + half * 16;   // 0..31, 8 features each
            f16x8 vh[5], vl[5];
            #pragma unroll
            for (int c = 0; c < 8; ++c) {
                const int j = jg * 8 + c;
                const float wx = w0[0 * WIDTH + j];
                const float wy = w0[1 * WIDTH + j];
                const float wt = w0[2 * WIDTH + j];
                float zv, s;
                tanh_s(fmaf(x, wx, fmaf(y, wy, fmaf(t, wt, b0[j]))), zv, s);
                const float vals[5] = { zv, s * wx, s * wy, s * wt,
                                        -2.0f * zv * s * (wx * wx + wy * wy) };
                #pragma unroll
                for (int v = 0; v < 5; ++v) {
                    _Float16 h, lo;
                    split2(vals[v], h, lo);
                    vh[v][c] = h; vl[v][c] = lo;
                }
            }
            #pragma unroll
            for (int v = 0; v < 5; ++v) {
                const int off = ((v * 8 + (jg >> 2)) * 64 + (jg & 3) * 16 + p) * 8;
                *(f16x8*)(Zm + off)          = vh[v];
                *(f16x8*)(Zm + CPLANE + off) = vl[v];
            }
        }
    }
    __syncthreads();

    // ---------------- hidden layers: anti-phased K/E pipeline ---------------
    f32x4 acc[5][4];

    auto zacc = [&]() {
        #pragma unroll
        for (int v = 0; v < 5; ++v)
            #pragma unroll
            for (int Mt = 0; Mt < 4; ++Mt)
                acc[v][Mt] = (f32x4){0.f, 0.f, 0.f, 0.f};
    };

    auto kstage = [&](int l) {
        const _Float16* Wl = wt2 + l * 2 * 65536;
        #pragma unroll 2
        for (int kc = 0; kc < 8; ++kc) {
            f16x8 Ah[4], Al[4];
            #pragma unroll
            for (int Mt = 0; Mt < 4; ++Mt) {
                const int fo = (((gwv * 4 + Mt) * 8 + kc) * 64 + lane) * 8;
                Ah[Mt] = *(const f16x8*)(Wl + fo);
                Al[Mt] = *(const f16x8*)(Wl + 65536 + fo);
            }
            #pragma unroll
            for (int v = 0; v < 5; ++v) {
                const int zo = ((v * 8 + kc) * 64 + lane) * 8;
                const f16x8 Bh = *(const f16x8*)(Zm + zo);
                const f16x8 Bl = *(const f16x8*)(Zm + CPLANE + zo);
                #pragma unroll
                for (int Mt = 0; Mt < 4; ++Mt) {
                    f32x4 a = acc[v][Mt];
                    a = __builtin_amdgcn_mfma_f32_16x16x32_f16(Ah[Mt], Bl, a, 0, 0, 0);
                    a = __builtin_amdgcn_mfma_f32_16x16x32_f16(Al[Mt], Bh, a, 0, 0, 0);
                    a = __builtin_amdgcn_mfma_f32_16x16x32_f16(Ah[Mt], Bh, a, 0, 0, 0);
                    acc[v][Mt] = a;
                }
            }
        }
    };

    auto estage = [&](int l) {
        const float* Bb = Bsl[l];
        #pragma unroll
        for (int Mt = 0; Mt < 4; ++Mt) {
            const int jt = gwv * 4 + Mt;
            float nv[5][4];
            #pragma unroll
            for (int reg = 0; reg < 4; ++reg) {
                const int j = jt * 16 + q * 4 + reg;
                float zv, s;
                tanh_s(acc[0][Mt][reg] + Bb[j], zv, s);
                const float u1 = acc[1][Mt][reg];
                const float u2 = acc[2][Mt][reg];
                nv[0][reg] = zv;
                nv[1][reg] = s * u1;
                nv[2][reg] = s * u2;
                nv[3][reg] = s * acc[3][Mt][reg];
                nv[4][reg] = fmaf(-2.0f * zv * s, fmaf(u1, u1, u2 * u2),
                                  s * acc[4][Mt][reg]);
            }
            const int j0 = jt * 16 + q * 4;
            const int off0 = ((j0 >> 5) * 64 + ((j0 >> 3) & 3) * 16 + n15) * 8 + (j0 & 7);
            #pragma unroll
            for (int v = 0; v < 5; ++v) {
                const h16x2 h01 = __builtin_amdgcn_cvt_pkrtz(nv[v][0], nv[v][1]);
                const h16x2 h23 = __builtin_amdgcn_cvt_pkrtz(nv[v][2], nv[v][3]);
                const h16x2 l01 = __builtin_amdgcn_cvt_pkrtz(nv[v][0] - (float)h01[0],
                                                             nv[v][1] - (float)h01[1]);
                const h16x2 l23 = __builtin_amdgcn_cvt_pkrtz(nv[v][2] - (float)h23[0],
                                                             nv[v][3] - (float)h23[1]);
                *(f16x4*)(Zm + v * 4096 + off0) =
                    (f16x4){ (_Float16)h01[0], (_Float16)h01[1],
                             (_Float16)h23[0], (_Float16)h23[1] };
                *(f16x4*)(Zm + CPLANE + v * 4096 + off0) =
                    (f16x4){ (_Float16)l01[0], (_Float16)l01[1],
                             (_Float16)l23[0], (_Float16)l23[1] };
            }
        }
    };

    // Schedule (gang A half a layer ahead):
    //  ph:  1     2      3      4      5      6      7      8      9     10    11
    //  A : K0  |  E0  |  K1  |  E1  |  K2  |  E2  |  K3  |  E3  |  K4  |  E4 |  -
    //  B :  -  |  K0  |  E0  |  K1  |  E1  |  K2  |  E2  |  K3  |  E3  |  K4 |  E4
    if (isA) { zacc(); kstage(0); }
    __syncthreads();
    for (int l = 1; l <= 4; ++l) {
        if (isA) estage(l - 1); else { zacc(); kstage(l - 1); }
        __syncthreads();
        if (isA) { zacc(); kstage(l); } else estage(l - 1);
        __syncthreads();
    }
    if (isA) estage(4); else { zacc(); kstage(4); }
    __syncthreads();
    if (!isA) estage(4);
    __syncthreads();

    // ---------------- final layer: (256 -> 1), each gang its own tile --------
    float partial = 0.f;
    const int n    = gtid >> 1;       // row 0..79 (valid if gtid < 160)
    const int half = gtid & 1;
    if (gtid < 2 * NROW) {
        const int v = n >> 4, p = n & 15;
        for (int kk = half * 128; kk < half * 128 + 128; kk += 8) {
            const int off = ((v * 8 + (kk >> 5)) * 64 + ((kk >> 3) & 3) * 16 + p) * 8;
            const f16x8 zh = *(const f16x8*)(Zm + off);
            const f16x8 zl = *(const f16x8*)(Zm + CPLANE + off);
            #pragma unroll
            for (int i = 0; i < 8; ++i)
                partial = fmaf((float)zh[i] + (float)zl[i], w6[kk + i], partial);
        }
    }
    __syncthreads();                 // all Z reads done before aliasing redf
    if (gtid < 2 * NROW) redf[half * NROW + n] = partial;
    __syncthreads();
    if (gtid < NROW) redf[2 * NROW + gtid] = redf[gtid] + redf[NROW + gtid];
    __syncthreads();

    // ---------------- residual: each gang its 16 points ----------------
    if (gtid < PTS) {
        const int p = gtid;
        const float* tot = redf + 2 * NROW;
        const float h   = tot[0 * 16 + p] + b6[0];
        const float hx  = tot[1 * 16 + p];
        const float hy  = tot[2 * 16 + p];
        const float ht  = tot[3 * 16 + p];
        const float lap = tot[4 * 16 + p];
        const float x = xyt[(gp0 + p) * 3 + 0];
        const float y = xyt[(gp0 + p) * 3 + 1];
        const float t = xyt[(gp0 + p) * 3 + 2];
        const float pi = 3.14159265358979323846f;
        const float f = sinf(pi * x) * sinf(pi * y) * expf(-t);
        out[gp0 + p] = ht - 0.5f * (fmaf(h, lap, fmaf(hx, hx, hy * hy))) - f;
    }
}

extern "C" void kernel_launch(void* const* d_in, const int* in_sizes, int n_in,
                              void* d_out, int out_size, void* d_ws, size_t ws_size,
                              hipStream_t stream) {
    const float* xyt = (const float*)d_in[0];
    const float* w0  = (const float*)d_in[1];
    const float* b0  = (const float*)d_in[2];
    const float* w1  = (const float*)d_in[3];
    const float* b1  = (const float*)d_in[4];
    const float* w2  = (const float*)d_in[5];
    const float* b2  = (const float*)d_in[6];
    const float* w3  = (const float*)d_in[7];
    const float* b3  = (const float*)d_in[8];
    const float* w4  = (const float*)d_in[9];
    const float* b4  = (const float*)d_in[10];
    const float* w5  = (const float*)d_in[11];
    const float* b5  = (const float*)d_in[12];
    const float* w6  = (const float*)d_in[13];
    const float* b6  = (const float*)d_in[14];
    float* out = (float*)d_out;
    _Float16* wt2 = (_Float16*)d_ws;    // needs 5*2*65536*2 = 1,310,720 B

    prep_w_kernel<<<160, 256, 0, stream>>>(w1, w2, w3, w4, w5, wt2);

    const int npts = in_sizes[0] / 3;   // 131072
    dim3 grid(npts / (PTS * 2));        // 4096 blocks x 2 tiles
    dim3 block(512);
    pde_mfma_kernel<<<grid, block, 0, stream>>>(xyt, w0, b0, b1, b2, b3, b4, b5,
                                                w6, b6, wt2, out);
}